// Round 2
// baseline (476.995 us; speedup 1.0000x reference)
//
#include <hip/hip_runtime.h>
#include <math.h>

// DynamicHybridRouter: logits = x @ gate_w^T + gate_b; top-2 routing (or temp softmax
// if any expert immature). x:[16384,2048] f32, gate_w:[64,2048] f32, gate_b:[64] f32.
//
// R2: 1024 blocks x 256 threads (BM=16 rows/block) -> 4 blocks/CU (grid was the
// occupancy cap at 512). K-loop barriers REMOVED: each wave stages w into its own
// private LDS slab, so only same-wave DS ordering (in-order pipe) is required.
// Software pipeline: w chunk c+1 prefetched into registers during compute of c;
// x prefetched one k4-step ahead. 3 barriers total (epilogue only).

#define NROWS 16384
#define DIM   2048
#define NEXP  64
#define BM    16            // rows per block
#define KSLICE 512          // K depth per wave
#define BK    32            // K chunk staged per iteration
#define NCHUNK (KSLICE / BK) // 16

__global__ __launch_bounds__(256, 4)
void router_kernel(const float* __restrict__ x,
                   const float* __restrict__ gw,
                   const float* __restrict__ gb,
                   const int* __restrict__ mat,
                   float* __restrict__ out) {
  // Per-wave private w slab: 64 experts x BK floats = 2048 floats (8KB) x 4 waves.
  // After the K loop (one barrier), reused as partial-logit storage:
  //   partials: [0..4096) = wave w at w*1024, 16 rows x 64 experts
  //   final logits: [4096..5120)
  __shared__ float slab[4 * NEXP * BK];
  __shared__ float p_a[BM], p_b[BM];
  __shared__ int   p_i[BM], p_j[BM];
  __shared__ int   s_flag;

  const int tid  = threadIdx.x;
  const int wave = tid >> 6;
  const int lane = tid & 63;
  const int te   = lane & 15;   // expert group: experts 4*te .. 4*te+3
  const int tr   = lane >> 4;   // row group: rows 4*tr .. 4*tr+3
  const int g    = te & 7;      // LDS swizzle key
  const int row0 = blockIdx.x * BM;
  const int kbase = wave * KSLICE;

  if (wave == 0) {
    unsigned long long b = __ballot(mat[lane] == 0);
    if (lane == 0) s_flag = (b != 0ull) ? 1 : 0;
  }

  float acc[4][4];
#pragma unroll
  for (int i = 0; i < 4; ++i)
#pragma unroll
    for (int j = 0; j < 4; ++j) acc[i][j] = 0.0f;

  float* wslab = slab + wave * (NEXP * BK);

  // Per-lane staging slots: slot it -> f = it*64+lane, e = f>>3, k4 = f&7.
  // Global offset (minus chunk): e*DIM + kbase + 4*k4. LDS offset (XOR-swizzled
  // so compute-side b128 reads are spread): e*BK + 4*(k4 ^ ((e>>2)&7)).
  int goff[8], loff[8];
#pragma unroll
  for (int it = 0; it < 8; ++it) {
    int f  = it * 64 + lane;
    int e  = f >> 3;
    int k4 = f & 7;
    goff[it] = e * DIM + kbase + 4 * k4;
    loff[it] = e * BK + 4 * (k4 ^ ((e >> 2) & 7));
  }

  // prefetch chunk 0 into registers
  float4 wreg[8];
#pragma unroll
  for (int it = 0; it < 8; ++it) wreg[it] = *(const float4*)(gw + goff[it]);

  const float* xbase0 = x + (size_t)(row0 + 4 * tr) * DIM + kbase;

#pragma unroll 1
  for (int c = 0; c < NCHUNK; ++c) {
    // commit current chunk to this wave's private slab (in-order DS pipe:
    // prior chunk's reads were issued first, no barrier needed)
#pragma unroll
    for (int it = 0; it < 8; ++it) *(float4*)(wslab + loff[it]) = wreg[it];

    // prefetch next chunk (clamped re-fetch on the last iteration, branch-free)
    const int cn = (c + 1 < NCHUNK) ? (c + 1) : c;
#pragma unroll
    for (int it = 0; it < 8; ++it)
      wreg[it] = *(const float4*)(gw + goff[it] + cn * BK);

    const float* xb = xbase0 + c * BK;
    float4 xv[4];
#pragma unroll
    for (int i = 0; i < 4; ++i) xv[i] = *(const float4*)(xb + (size_t)i * DIM);

#pragma unroll
    for (int k4 = 0; k4 < 8; ++k4) {
      float4 xn[4];
      if (k4 < 7) {
#pragma unroll
        for (int i = 0; i < 4; ++i)
          xn[i] = *(const float4*)(xb + (size_t)i * DIM + 4 * (k4 + 1));
      }
      float4 bw[4];
#pragma unroll
      for (int j = 0; j < 4; ++j)
        bw[j] = *(const float4*)(wslab + (4 * te + j) * BK + 4 * (k4 ^ g));
#pragma unroll
      for (int i = 0; i < 4; ++i) {
#pragma unroll
        for (int j = 0; j < 4; ++j) {
          acc[i][j] = fmaf(xv[i].x, bw[j].x,
                      fmaf(xv[i].y, bw[j].y,
                      fmaf(xv[i].z, bw[j].z,
                      fmaf(xv[i].w, bw[j].w, acc[i][j]))));
        }
      }
      if (k4 < 7) {
#pragma unroll
        for (int i = 0; i < 4; ++i) xv[i] = xn[i];
      }
    }
  }

  // partial regions overlap other waves' slabs -> barrier before the store
  __syncthreads();
#pragma unroll
  for (int i = 0; i < 4; ++i) {
    float4 v = make_float4(acc[i][0], acc[i][1], acc[i][2], acc[i][3]);
    *(float4*)(slab + wave * (BM * NEXP) + (4 * tr + i) * NEXP + 4 * te) = v;
  }
  __syncthreads();

  // cross-wave reduction + bias -> final logits at slab+4096
  for (int idx = tid; idx < BM * NEXP; idx += 256) {
    float v = slab[idx] + slab[1024 + idx] + slab[2048 + idx] + slab[3072 + idx]
            + gb[idx & (NEXP - 1)];
    slab[4096 + idx] = v;
  }
  __syncthreads();

  const int flag = s_flag;
  const float* logits = slab + 4096;

  // per-row routing (threads 0..15; rotated scan breaks same-bank row scans)
  if (tid < BM) {
    const float* rowp = logits + tid * NEXP;
    if (flag == 0) {
      float m1 = -1e30f, m2 = -1e30f;
      int i1 = 0, i2 = 0;
      for (int ee = 0; ee < NEXP; ++ee) {
        int e = (ee + tid) & (NEXP - 1);
        float v = rowp[e];
        if (v > m1) { m2 = m1; i2 = i1; m1 = v; i1 = e; }
        else if (v > m2) { m2 = v; i2 = e; }
      }
      float t = expf(m2 - m1);
      float pa = 1.0f / (1.0f + t);
      p_a[tid] = pa;
      p_b[tid] = t * pa;
      p_i[tid] = i1;
      p_j[tid] = i2;
    } else {
      float mx = -1e30f;
      for (int ee = 0; ee < NEXP; ++ee) {
        int e = (ee + tid) & (NEXP - 1);
        mx = fmaxf(mx, rowp[e]);
      }
      float s = 0.0f;
      for (int ee = 0; ee < NEXP; ++ee) {
        int e = (ee + tid) & (NEXP - 1);
        s += expf((rowp[e] - mx) * 0.5f);  // /TEMPERATURE=2.0
      }
      p_a[tid] = mx;
      p_b[tid] = 1.0f / s;
    }
  }
  __syncthreads();

  // coalesced float4 writes of the 16x64 tile (exactly 256 quads, one per thread)
  {
    int q  = tid;
    int r  = q >> 4;
    int e0 = (q & 15) * 4;
    float4 v;
    if (flag == 0) {
      int i1 = p_i[r], i2 = p_j[r];
      float a = p_a[r], b = p_b[r];
      v.x = (e0 + 0 == i1) ? a : (e0 + 0 == i2) ? b : 0.0f;
      v.y = (e0 + 1 == i1) ? a : (e0 + 1 == i2) ? b : 0.0f;
      v.z = (e0 + 2 == i1) ? a : (e0 + 2 == i2) ? b : 0.0f;
      v.w = (e0 + 3 == i1) ? a : (e0 + 3 == i2) ? b : 0.0f;
    } else {
      float mx = p_a[r], inv = p_b[r];
      float4 lv = *(const float4*)(logits + r * NEXP + e0);
      v.x = expf((lv.x - mx) * 0.5f) * inv;
      v.y = expf((lv.y - mx) * 0.5f) * inv;
      v.z = expf((lv.z - mx) * 0.5f) * inv;
      v.w = expf((lv.w - mx) * 0.5f) * inv;
    }
    *(float4*)(out + (size_t)(row0 + r) * NEXP + e0) = v;
  }
}

extern "C" void kernel_launch(void* const* d_in, const int* in_sizes, int n_in,
                              void* d_out, int out_size, void* d_ws, size_t ws_size,
                              hipStream_t stream) {
  const float* x  = (const float*)d_in[0];
  const float* gw = (const float*)d_in[1];
  const float* gb = (const float*)d_in[2];
  const int*   mt = (const int*)d_in[3];
  float* outp = (float*)d_out;
  (void)in_sizes; (void)n_in; (void)d_ws; (void)ws_size; (void)out_size;

  dim3 grid(NROWS / BM);   // 1024 blocks
  dim3 block(256);
  router_kernel<<<grid, block, 0, stream>>>(x, gw, gb, mt, outp);
}

// Round 3
// 210.430 us; speedup vs baseline: 2.2668x; 2.2668x over previous
//
#include <hip/hip_runtime.h>
#include <math.h>

// DynamicHybridRouter via bf16-split MFMA.
// logits = x @ gate_w^T + gate_b; top-2 routing (temp softmax if any expert immature).
// x:[16384,2048] f32 (134MB, the HBM stream), gate_w:[64,2048] f32, out:[16384,64] f32.
//
// fp32 product via 3-term bf16 split: x=xh+xl, w=wh+wl; x*w ~= xh*wh + xh*wl + xl*wh
// (dropped xl*wl ~ 2^-16 rel; logit err ~3e-5 << 1.89e-2 threshold).
// Prologue kernel splits w ONCE into B-fragment-ordered bf16 hi/lo arrays in d_ws
// (512KB, L2-resident; main-kernel B loads = 1KB fully-coalesced b128 per instr).
// Main: 512 blocks x 512 thr (8 waves), BM=32 rows/block, 8-way K-split (256/wave),
// 16x16x32 bf16 MFMA, acc 2 row-tiles x 4 expert-tiles. 2 blocks/CU = 4 waves/SIMD.
// R2 lesson: WRITE_SIZE 504MB was VGPR spill under launch_bounds(256,4)@64VGPR.
// Here the K-loop working set is ~112 VGPR under the 128 cap of (512,4).

#define NROWS 16384
#define DIM   2048
#define NEXP  64
#define BM    32
#define TPB   512
#define KSLICE 256
#define KSTEPS (KSLICE / 32)   // 8 MFMA steps per wave

typedef __attribute__((ext_vector_type(4))) float f32x4;
typedef __attribute__((ext_vector_type(8))) short bf16x8;

// ---- prologue: w [64][2048] f32 -> B-frag-ordered bf16 hi/lo in ws ----
// frag slot = ((kstep*4 + t)*64 + lane), holds 8 bf16: w[e=16t+(lane&15)]
// [k = kstep*32 + (lane>>4)*8 + j], j=0..7.  16384 slots x 16B per array.
__global__ void wfrag_kernel(const float* __restrict__ gw,
                             unsigned short* __restrict__ wsH,
                             unsigned short* __restrict__ wsL) {
  int slot  = blockIdx.x * 256 + threadIdx.x;   // 0..16383
  int lane  = slot & 63;
  int t     = (slot >> 6) & 3;
  int kstep = slot >> 8;
  int e  = 16 * t + (lane & 15);
  int k0 = kstep * 32 + (lane >> 4) * 8;
  const float* src = gw + (size_t)e * DIM + k0;
  bf16x8 vh, vl;
#pragma unroll
  for (int j = 0; j < 8; ++j) {
    float w = src[j];
    unsigned u = __float_as_uint(w);
    vh[j] = (short)(u >> 16);                       // truncate-to-bf16
    float hi = __uint_as_float(u & 0xffff0000u);
    float rl = w - hi;                              // exact residual (<=15 mant bits)
    vl[j] = (short)(__float_as_uint(rl) >> 16);
  }
  ((bf16x8*)wsH)[slot] = vh;
  ((bf16x8*)wsL)[slot] = vl;
}

// ---- main kernel ----
__global__ __launch_bounds__(TPB, 4)
void router_mfma(const float* __restrict__ x,
                 const unsigned short* __restrict__ wsH,
                 const unsigned short* __restrict__ wsL,
                 const float* __restrict__ gb,
                 const int* __restrict__ mat,
                 float* __restrict__ out) {
  __shared__ float slab[4 * BM * NEXP];   // 4 partial slabs, 32KB; slab0 -> logits
  __shared__ float p_a[BM], p_b[BM];
  __shared__ int   p_i[BM], p_j[BM];
  __shared__ int   s_flag;

  const int tid  = threadIdx.x;
  const int wave = tid >> 6;     // 0..7 -> K-slice
  const int lane = tid & 63;
  const int m    = lane & 15;    // row within tile / expert within tile
  const int kg   = lane >> 4;    // k-group (quad)
  const int row0 = blockIdx.x * BM;

  if (tid < 64) {
    unsigned long long b = __ballot(mat[lane] == 0);
    if (lane == 0) s_flag = (b != 0ull) ? 1 : 0;
  }

  f32x4 acc[2][4];
#pragma unroll
  for (int r = 0; r < 2; ++r)
#pragma unroll
    for (int t = 0; t < 4; ++t) acc[r][t] = (f32x4)0.0f;

  // B-frag pointers: slot = ((kstep*4 + t)*64 + lane); this wave's kstep base = wave*KSTEPS
  const bf16x8* bHp = (const bf16x8*)wsH + (size_t)(wave * KSTEPS * 4) * 64 + lane;
  const bf16x8* bLp = (const bf16x8*)wsL + (size_t)(wave * KSTEPS * 4) * 64 + lane;

  // x: lane covers A[m][kg*8+j]; row-tiles r in {0,1} -> rows row0+16r+m
  const float* xb = x + (size_t)(row0 + m) * DIM + wave * KSLICE + kg * 8;

  // prefetch step 0 raw x (2 row-tiles x 8 floats)
  float4 xr[2][2];
  xr[0][0] = *(const float4*)(xb);
  xr[0][1] = *(const float4*)(xb + 4);
  xr[1][0] = *(const float4*)(xb + 16 * DIM);
  xr[1][1] = *(const float4*)(xb + 16 * DIM + 4);

#pragma unroll
  for (int s = 0; s < KSTEPS; ++s) {
    // convert current x to hi/lo bf16 A-frags (before prefetch overwrites xr)
    bf16x8 ah[2], al[2];
#pragma unroll
    for (int r = 0; r < 2; ++r) {
#pragma unroll
      for (int q = 0; q < 2; ++q) {
        float4 v = xr[r][q];
        float f0 = v.x, f1 = v.y, f2 = v.z, f3 = v.w;
        float ff[4] = {f0, f1, f2, f3};
#pragma unroll
        for (int j = 0; j < 4; ++j) {
          unsigned u = __float_as_uint(ff[j]);
          ah[r][q * 4 + j] = (short)(u >> 16);
          float hi = __uint_as_float(u & 0xffff0000u);
          float rl = ff[j] - hi;
          al[r][q * 4 + j] = (short)(__float_as_uint(rl) >> 16);
        }
      }
    }
    // load B frags for this step (fully coalesced 1KB/instr, L2-resident)
    bf16x8 bh[4], bl[4];
#pragma unroll
    for (int t = 0; t < 4; ++t) {
      bh[t] = bHp[(size_t)s * 256 + t * 64];
      bl[t] = bLp[(size_t)s * 256 + t * 64];
    }
    // prefetch next step's raw x (HBM) while MFMAs run
    if (s + 1 < KSTEPS) {
      const float* xn = xb + (s + 1) * 32;
      xr[0][0] = *(const float4*)(xn);
      xr[0][1] = *(const float4*)(xn + 4);
      xr[1][0] = *(const float4*)(xn + 16 * DIM);
      xr[1][1] = *(const float4*)(xn + 16 * DIM + 4);
    }
    // 3-term MFMA accumulate
#pragma unroll
    for (int r = 0; r < 2; ++r) {
#pragma unroll
      for (int t = 0; t < 4; ++t) {
        acc[r][t] = __builtin_amdgcn_mfma_f32_16x16x32_bf16(ah[r], bh[t], acc[r][t], 0, 0, 0);
        acc[r][t] = __builtin_amdgcn_mfma_f32_16x16x32_bf16(ah[r], bl[t], acc[r][t], 0, 0, 0);
        acc[r][t] = __builtin_amdgcn_mfma_f32_16x16x32_bf16(al[r], bh[t], acc[r][t], 0, 0, 0);
      }
    }
  }

  // ---- cross-wave reduction: C/D layout col=lane&15, row=(lane>>4)*4+reg ----
  if (wave >= 4) {
    float* sl = slab + (wave - 4) * (BM * NEXP);
#pragma unroll
    for (int r = 0; r < 2; ++r)
#pragma unroll
      for (int t = 0; t < 4; ++t)
#pragma unroll
        for (int reg = 0; reg < 4; ++reg)
          sl[(16 * r + kg * 4 + reg) * NEXP + 16 * t + m] = acc[r][t][reg];
  }
  __syncthreads();
  if (wave < 4) {
    float* sl = slab + wave * (BM * NEXP);
#pragma unroll
    for (int r = 0; r < 2; ++r)
#pragma unroll
      for (int t = 0; t < 4; ++t)
#pragma unroll
        for (int reg = 0; reg < 4; ++reg)
          sl[(16 * r + kg * 4 + reg) * NEXP + 16 * t + m] += acc[r][t][reg];
  }
  __syncthreads();
  // 4 slabs + bias -> logits in slab[0..2048)
  for (int idx = tid; idx < BM * NEXP; idx += TPB) {
    float v = slab[idx] + slab[2048 + idx] + slab[4096 + idx] + slab[6144 + idx]
            + gb[idx & (NEXP - 1)];
    slab[idx] = v;
  }
  __syncthreads();

  const int flag = s_flag;

  // per-row routing (threads 0..31; rotated scan spreads banks)
  if (tid < BM) {
    const float* rowp = slab + tid * NEXP;
    if (flag == 0) {
      float m1 = -1e30f, m2 = -1e30f;
      int i1 = 0, i2 = 0;
      for (int ee = 0; ee < NEXP; ++ee) {
        int e = (ee + tid) & (NEXP - 1);
        float v = rowp[e];
        if (v > m1) { m2 = m1; i2 = i1; m1 = v; i1 = e; }
        else if (v > m2) { m2 = v; i2 = e; }
      }
      float t = expf(m2 - m1);
      float pa = 1.0f / (1.0f + t);
      p_a[tid] = pa;
      p_b[tid] = t * pa;
      p_i[tid] = i1;
      p_j[tid] = i2;
    } else {
      float mx = -1e30f;
      for (int ee = 0; ee < NEXP; ++ee)
        mx = fmaxf(mx, rowp[(ee + tid) & (NEXP - 1)]);
      float ssum = 0.0f;
      for (int ee = 0; ee < NEXP; ++ee)
        ssum += expf((rowp[(ee + tid) & (NEXP - 1)] - mx) * 0.5f);  // /T=2
      p_a[tid] = mx;
      p_b[tid] = 1.0f / ssum;
    }
  }
  __syncthreads();

  // output: 32x64 tile = 512 float4, one per thread
  {
    int q  = tid;
    int r  = q >> 4;
    int e0 = (q & 15) * 4;
    float4 v;
    if (flag == 0) {
      int i1 = p_i[r], i2 = p_j[r];
      float a = p_a[r], b = p_b[r];
      v.x = (e0 + 0 == i1) ? a : (e0 + 0 == i2) ? b : 0.0f;
      v.y = (e0 + 1 == i1) ? a : (e0 + 1 == i2) ? b : 0.0f;
      v.z = (e0 + 2 == i1) ? a : (e0 + 2 == i2) ? b : 0.0f;
      v.w = (e0 + 3 == i1) ? a : (e0 + 3 == i2) ? b : 0.0f;
    } else {
      float mx = p_a[r], inv = p_b[r];
      const float* rowp = slab + r * NEXP + e0;
      v.x = expf((rowp[0] - mx) * 0.5f) * inv;
      v.y = expf((rowp[1] - mx) * 0.5f) * inv;
      v.z = expf((rowp[2] - mx) * 0.5f) * inv;
      v.w = expf((rowp[3] - mx) * 0.5f) * inv;
    }
    *(float4*)(out + (size_t)(row0 + r) * NEXP + e0) = v;
  }
}

extern "C" void kernel_launch(void* const* d_in, const int* in_sizes, int n_in,
                              void* d_out, int out_size, void* d_ws, size_t ws_size,
                              hipStream_t stream) {
  const float* x  = (const float*)d_in[0];
  const float* gw = (const float*)d_in[1];
  const float* gb = (const float*)d_in[2];
  const int*   mt = (const int*)d_in[3];
  float* outp = (float*)d_out;
  (void)in_sizes; (void)n_in; (void)out_size; (void)ws_size;

  // ws layout: [0,256KB) = wh frags, [256KB,512KB) = wl frags
  unsigned short* wsH = (unsigned short*)d_ws;
  unsigned short* wsL = wsH + 64 * DIM;

  wfrag_kernel<<<64, 256, 0, stream>>>(gw, wsH, wsL);
  router_mfma<<<NROWS / BM, TPB, 0, stream>>>(x, wsH, wsL, gb, mt, outp);
}